// Round 14
// baseline (1157.470 us; speedup 1.0000x reference)
//
#include <hip/hip_runtime.h>
#include <cmath>

#define BB 16
#define CC 128
#define HH 128
#define WW 128
#define NN 1024
#define SS 256
#define BN (BB*NN)
#define K1 192            // first-layer K padded: 130 -> 192 (3 x 64)

typedef short short8v __attribute__((ext_vector_type(8)));
typedef float f32x4 __attribute__((ext_vector_type(4)));
typedef unsigned short u16;
typedef unsigned char u8;

__device__ __forceinline__ u16 f2bf(float f) {
    unsigned u = __builtin_bit_cast(unsigned, f);
    unsigned r = (u + 0x7FFFu + ((u >> 16) & 1u)) >> 16;
    return (u16)r;
}
__device__ __forceinline__ float bf2f(u16 h) {
    unsigned u = ((unsigned)h) << 16;
    return __builtin_bit_cast(float, u);
}

// ---------------------------------------------------------------------------
// casts
// ---------------------------------------------------------------------------
__global__ void k_cast4(const float* __restrict__ s, u16* __restrict__ d, long n4) {
    long i = (long)blockIdx.x * blockDim.x + threadIdx.x;
    long st = (long)gridDim.x * blockDim.x;
    for (; i < n4; i += st) {
        float4 v = ((const float4*)s)[i];
        ushort4 o;
        o.x = f2bf(v.x); o.y = f2bf(v.y); o.z = f2bf(v.z); o.w = f2bf(v.w);
        ((ushort4*)d)[i] = o;
    }
}

// adj f32 -> u8 fixed point: q = round(adj * 2^18); also zeroes the grid bar.
__global__ void k_castA8(const float* __restrict__ s, u8* __restrict__ d, long n4,
                         int* __restrict__ bar) {
    if (blockIdx.x == 0 && threadIdx.x == 0) *bar = 0;
    long i = (long)blockIdx.x * blockDim.x + threadIdx.x;
    long st = (long)gridDim.x * blockDim.x;
    for (; i < n4; i += st) {
        float4 v = ((const float4*)s)[i];
        uchar4 o;
        o.x = (u8)min(255, (int)(v.x * 262144.f + 0.5f));
        o.y = (u8)min(255, (int)(v.y * 262144.f + 0.5f));
        o.z = (u8)min(255, (int)(v.z * 262144.f + 0.5f));
        o.w = (u8)min(255, (int)(v.w * 262144.f + 0.5f));
        ((uchar4*)d)[i] = o;
    }
}

// first_W [2][256][130] -> bf16 [2][256][192] zero-padded
__global__ void k_castW1(const float* __restrict__ s, u16* __restrict__ d) {
    int idx = blockIdx.x * blockDim.x + threadIdx.x;
    if (idx >= 2 * 256 * K1) return;
    int k = idx % K1, r = idx / K1;
    d[idx] = (k < 130) ? f2bf(s[r * 130 + k]) : (u16)0;
}

// ---------------------------------------------------------------------------
// features [16][128][16384] f32 -> featT [16][16384][128] bf16 (tiled transpose)
// ---------------------------------------------------------------------------
__global__ __launch_bounds__(256) void k_ftrans(const float* __restrict__ f,
                                                u16* __restrict__ ft) {
    __shared__ u16 T[128][132];
    int b = blockIdx.y, hw0 = blockIdx.x * 128;
    int t = threadIdx.x;
    const float* fb = f + (long)b * CC * (HH * WW);
    #pragma unroll
    for (int p = 0; p < 16; ++p) {
        int c = p * 8 + (t >> 5);
        int x = (t & 31) * 4;
        float4 v = *(const float4*)(fb + (long)c * (HH * WW) + hw0 + x);
        T[x + 0][c] = f2bf(v.x); T[x + 1][c] = f2bf(v.y);
        T[x + 2][c] = f2bf(v.z); T[x + 3][c] = f2bf(v.w);
    }
    __syncthreads();
    #pragma unroll
    for (int p = 0; p < 8; ++p) {
        int hw = p * 16 + (t >> 4);
        int c8 = (t & 15) * 8;
        short8v v = *(const short8v*)&T[hw][c8];
        *(short8v*)(ft + ((long)b * 16384 + hw0 + hw) * 128 + c8) = v;
    }
}

// ---------------------------------------------------------------------------
// interp: wave per node; lane = (corner<<4)|chunk. writes Xh [BN][192]
// ---------------------------------------------------------------------------
__global__ __launch_bounds__(256) void k_interp(const u16* __restrict__ featT,
                                                const float* __restrict__ base_point,
                                                u16* __restrict__ Xh) {
    int t = threadIdx.x;
    int lane = t & 63, w = t >> 6;
    int bn = blockIdx.x * 4 + w;
    int b = bn >> 10;
    float px = base_point[bn * 2 + 0];
    float py = base_point[bn * 2 + 1];
    float Xs = px * WW, Ys = py * HH;
    float X0f = floorf(Xs), Y0f = floorf(Ys);
    float fx = Xs - X0f, fy = Ys - Y0f;
    int x0 = min(max((int)X0f, 0), WW - 1);
    int x1 = min(max((int)(X0f + 1.f), 0), WW - 1);
    int y0 = min(max((int)Y0f, 0), HH - 1);
    int y1 = min(max((int)(Y0f + 1.f), 0), HH - 1);
    int corner = lane >> 4, chunk = lane & 15;
    int xi = (corner & 2) ? x1 : x0;
    int yi = (corner & 1) ? y1 : y0;
    float wgt = ((corner & 2) ? fx : 1.f - fx) * ((corner & 1) ? fy : 1.f - fy);
    const u16* fp = featT + ((long)b * 16384 + yi * WW + xi) * 128 + chunk * 8;
    short8v v = *(const short8v*)fp;
    float a[8];
    #pragma unroll
    for (int j = 0; j < 8; ++j) a[j] = wgt * bf2f((u16)v[j]);
    #pragma unroll
    for (int j = 0; j < 8; ++j) {
        a[j] += __shfl_xor(a[j], 16);
        a[j] += __shfl_xor(a[j], 32);
    }
    if (lane < 16) {
        short8v o;
        #pragma unroll
        for (int j = 0; j < 8; ++j) o[j] = (short)f2bf(a[j]);
        *(short8v*)(Xh + (long)bn * K1 + chunk * 8) = o;
    } else if (lane < 24) {
        short8v o = {};
        if (lane == 16) { o[0] = (short)f2bf(px); o[1] = (short)f2bf(py); }
        *(short8v*)(Xh + (long)bn * K1 + 128 + (lane - 16) * 8) = o;
    }
}

// ---------------------------------------------------------------------------
// grid barrier: monotonic counter, release/acquire via __threadfence.
// SAFE: 96KB LDS forces 1 block/CU; grid=256=#CUs -> all blocks co-resident.
// ---------------------------------------------------------------------------
__device__ __forceinline__ void gbar(int* bar, int target) {
    __syncthreads();
    if (threadIdx.x == 0) {
        __threadfence();
        __hip_atomic_fetch_add(bar, 1, __ATOMIC_RELAXED, __HIP_MEMORY_SCOPE_AGENT);
        while (__hip_atomic_load(bar, __ATOMIC_RELAXED, __HIP_MEMORY_SCOPE_AGENT) < target)
            __builtin_amdgcn_s_sleep(8);
        __threadfence();
    }
    __syncthreads();
}

// ---------------------------------------------------------------------------
// MEGA kernel: all 28 GEMM phases (14x wg + 14x agg2), one launch.
// grid 256 x 512 threads, 96 KB LDS (forces 1 block/CU -> barrier-safe).
// wg phase: [Z|Y] = A @ W^T (2 tiles/block, 128x128, 3-stage, vmcnt(4));
//           Y written transposed to YT.
// agg phase: Out = relu(Z + adj(u8)@Y + b0+b1 [+res]) (R12 pipeline, vmcnt(3)).
// ---------------------------------------------------------------------------
__global__ __launch_bounds__(512) void k_mega(
    const u8* __restrict__ adjq,
    const u16* __restrict__ Xh,
    const u16* __restrict__ Whf,
    const u16* __restrict__ Whm,
    const u16* __restrict__ Whl,
    const float* __restrict__ first_b,
    const float* __restrict__ mid_b,
    const float* __restrict__ last_b,
    u16* __restrict__ Z, u16* __restrict__ YT,
    u16* __restrict__ Hn, u16* __restrict__ On,
    int* bar) {

    __shared__ u16 lds[49152];              // 96 KB
    int t = threadIdx.x;
    int lane = t & 63, w = t >> 6;
    int wr = w >> 1, wc = w & 1;

    // ---- wg phase: 512 tiles, 2 per block ----
    auto wg_phase = [&](const u16* A, int lda, int nK, const u16* W, int ldw) {
        for (int tl = 0; tl < 2; ++tl) {
            __syncthreads();                 // LDS quiet before restaging
            int h = blockIdx.x + (tl << 8);
            int bx = (h >> 3) & 3;
            int by = (h & 7) | ((h >> 5) << 3);
            int c0 = bx * 128;
            long row0 = (long)by * 128;
            f32x4 acc[2][4] = {};

            auto stage = [&](int s, int bufbase) {
                int kt = s * 64;
                u16* As = lds + bufbase;
                u16* Bs = lds + bufbase + 8192;
                #pragma unroll
                for (int q = 0; q < 2; ++q) {
                    int rb = w * 16 + q * 8;
                    int row = rb + (lane >> 3);
                    int koff = kt + (((lane & 7) ^ (row & 7)) << 3);
                    __builtin_amdgcn_global_load_lds(
                        (const __attribute__((address_space(1))) void*)(A + (row0 + row) * lda + koff),
                        (__attribute__((address_space(3))) void*)(As + rb * 64), 16, 0, 0);
                    __builtin_amdgcn_global_load_lds(
                        (const __attribute__((address_space(1))) void*)(W + (long)(c0 + row) * ldw + koff),
                        (__attribute__((address_space(3))) void*)(Bs + rb * 64), 16, 0, 0);
                }
            };

            stage(0, 0);
            if (nK > 1) stage(1, 16384);
            int curb = 0, stb = 32768;
            for (int s = 0; s < nK; ++s) {
                if (s + 1 < nK) { asm volatile("s_waitcnt vmcnt(4)" ::: "memory"); }
                else            { asm volatile("s_waitcnt vmcnt(0)" ::: "memory"); }
                __builtin_amdgcn_sched_barrier(0);
                __builtin_amdgcn_s_barrier();
                if (s + 2 < nK) stage(s + 2, stb);
                const u16* As = lds + curb;
                const u16* Bs = lds + curb + 8192;
                #pragma unroll
                for (int kk = 0; kk < 2; ++kk) {
                    short8v a[2], bfr[4];
                    #pragma unroll
                    for (int m = 0; m < 2; ++m) {
                        int row = wr * 32 + m * 16 + (lane & 15);
                        int sl = (kk * 4 + (lane >> 4)) ^ (row & 7);
                        a[m] = *(const short8v*)(As + row * 64 + sl * 8);
                    }
                    #pragma unroll
                    for (int n = 0; n < 4; ++n) {
                        int row = wc * 64 + n * 16 + (lane & 15);
                        int sl = (kk * 4 + (lane >> 4)) ^ (row & 7);
                        bfr[n] = *(const short8v*)(Bs + row * 64 + sl * 8);
                    }
                    #pragma unroll
                    for (int m = 0; m < 2; ++m)
                        #pragma unroll
                        for (int n = 0; n < 4; ++n)
                            acc[m][n] = __builtin_amdgcn_mfma_f32_16x16x32_bf16(
                                a[m], bfr[n], acc[m][n], 0, 0, 0);
                }
                curb += 16384; if (curb == 49152) curb = 0;
                stb  += 16384; if (stb  == 49152) stb  = 0;
            }

            int mbase = wr * 32, nbase = wc * 64;
            if (c0 < 256) {
                #pragma unroll
                for (int m = 0; m < 2; ++m)
                    #pragma unroll
                    for (int n = 0; n < 4; ++n)
                        #pragma unroll
                        for (int r = 0; r < 4; ++r) {
                            int rr = mbase + m * 16 + (lane >> 4) * 4 + r;
                            int cc = nbase + n * 16 + (lane & 15);
                            Z[(row0 + rr) * 256 + c0 + cc] = f2bf(acc[m][n][r]);
                        }
            } else {
                u16 (*T)[136] = (u16(*)[136])lds;
                __syncthreads();
                #pragma unroll
                for (int m = 0; m < 2; ++m)
                    #pragma unroll
                    for (int n = 0; n < 4; ++n)
                        #pragma unroll
                        for (int r = 0; r < 4; ++r) {
                            int rr = mbase + m * 16 + (lane >> 4) * 4 + r;
                            int cc = nbase + n * 16 + (lane & 15);
                            T[cc][rr] = f2bf(acc[m][n][r]);
                        }
                __syncthreads();
                int bb2 = (int)(row0 >> 10);
                long nodeBase = row0 & 1023;
                int fbase = c0 - 256;
                #pragma unroll
                for (int p = 0; p < 4; ++p) {
                    int c = p * 32 + (t >> 4);
                    int moff = (t & 15) * 8;
                    short8v vv = *(const short8v*)(&T[c][moff]);
                    *(short8v*)(YT + ((long)bb2 * 256 + fbase + c) * 1024 + nodeBase + moff) = vv;
                }
            }
        }
    };

    // ---- agg phase: 256 tiles, 1 per block ----
    auto agg_phase = [&](const float* b0, const float* b1,
                         const u16* res, u16* Out) {
        __syncthreads();
        const int BUF = 12288;
        int h = blockIdx.x;
        int bz = h & 15, tt2 = h >> 4;
        int bx = tt2 & 1, by = tt2 >> 1;
        long row0 = (long)by * 128;
        int c0 = bx * 128;

        const u8*  Ap = adjq + (long)bz * NN * NN;
        const u16* Bp = YT + (long)bz * 256 * 1024;
        long obase = (long)bz * NN * 256;

        f32x4 acc[2][4] = {};
        int ar = t >> 2, ac = t & 3;
        int ac_src = ac ^ ((ar & 7) >> 1);

        auto stage = [&](int s, int bufbase) {
            int kt = s * 64;
            u8*  As = (u8*)(lds + bufbase);
            u16* Bs = lds + bufbase + 4096;
            __builtin_amdgcn_global_load_lds(
                (const __attribute__((address_space(1))) void*)(Ap + (row0 + ar) * NN + kt + ac_src * 16),
                (__attribute__((address_space(3))) void*)(As + ar * 64 + ac * 16), 16, 0, 0);
            #pragma unroll
            for (int q = 0; q < 2; ++q) {
                int rb = w * 16 + q * 8;
                int row = rb + (lane >> 3);
                int koff = kt + (((lane & 7) ^ (row & 7)) << 3);
                __builtin_amdgcn_global_load_lds(
                    (const __attribute__((address_space(1))) void*)(Bp + (long)(c0 + row) * NN + koff),
                    (__attribute__((address_space(3))) void*)(Bs + rb * 64), 16, 0, 0);
            }
        };

        stage(0, 0);
        stage(1, BUF);
        int curb = 0, stb = 2 * BUF;
        for (int s = 0; s < 16; ++s) {
            if (s < 15) { asm volatile("s_waitcnt vmcnt(3)" ::: "memory"); }
            else        { asm volatile("s_waitcnt vmcnt(0)" ::: "memory"); }
            __builtin_amdgcn_sched_barrier(0);
            __builtin_amdgcn_s_barrier();
            if (s + 2 < 16) stage(s + 2, stb);
            const u8*  As = (const u8*)(lds + curb);
            const u16* Bs = lds + curb + 4096;
            #pragma unroll
            for (int kk = 0; kk < 2; ++kk) {
                short8v a[2], bfr[4];
                #pragma unroll
                for (int m = 0; m < 2; ++m) {
                    int row = wr * 32 + m * 16 + (lane & 15);
                    int sfull = kk * 4 + (lane >> 4);
                    int chunk = (sfull >> 1) ^ ((row & 7) >> 1);
                    const unsigned* pq = (const unsigned*)(As + row * 64 + chunk * 16 + (sfull & 1) * 8);
                    unsigned q0 = pq[0], q1 = pq[1];
                    unsigned od[4];
                    {
                        float f0 = (float)(q0 & 0xffu)         * 0x1p-18f;
                        float f1 = (float)((q0 >> 8) & 0xffu)  * 0x1p-18f;
                        float f2 = (float)((q0 >> 16) & 0xffu) * 0x1p-18f;
                        float f3 = (float)(q0 >> 24)           * 0x1p-18f;
                        od[0] = __builtin_amdgcn_perm(
                            __builtin_bit_cast(unsigned, f1), __builtin_bit_cast(unsigned, f0), 0x07060302u);
                        od[1] = __builtin_amdgcn_perm(
                            __builtin_bit_cast(unsigned, f3), __builtin_bit_cast(unsigned, f2), 0x07060302u);
                    }
                    {
                        float f0 = (float)(q1 & 0xffu)         * 0x1p-18f;
                        float f1 = (float)((q1 >> 8) & 0xffu)  * 0x1p-18f;
                        float f2 = (float)((q1 >> 16) & 0xffu) * 0x1p-18f;
                        float f3 = (float)(q1 >> 24)           * 0x1p-18f;
                        od[2] = __builtin_amdgcn_perm(
                            __builtin_bit_cast(unsigned, f1), __builtin_bit_cast(unsigned, f0), 0x07060302u);
                        od[3] = __builtin_amdgcn_perm(
                            __builtin_bit_cast(unsigned, f3), __builtin_bit_cast(unsigned, f2), 0x07060302u);
                    }
                    a[m] = __builtin_bit_cast(short8v, *(uint4*)od);
                }
                #pragma unroll
                for (int n = 0; n < 4; ++n) {
                    int row = wc * 64 + n * 16 + (lane & 15);
                    int sl = (kk * 4 + (lane >> 4)) ^ (row & 7);
                    bfr[n] = *(const short8v*)(Bs + row * 64 + sl * 8);
                }
                #pragma unroll
                for (int m = 0; m < 2; ++m)
                    #pragma unroll
                    for (int n = 0; n < 4; ++n)
                        acc[m][n] = __builtin_amdgcn_mfma_f32_16x16x32_bf16(
                            a[m], bfr[n], acc[m][n], 0, 0, 0);
            }
            curb += BUF; if (curb == 3 * BUF) curb = 0;
            stb  += BUF; if (stb  == 3 * BUF) stb  = 0;
        }

        int mbase = wr * 32, nbase = wc * 64;
        #pragma unroll
        for (int m = 0; m < 2; ++m)
            #pragma unroll
            for (int n = 0; n < 4; ++n)
                #pragma unroll
                for (int r = 0; r < 4; ++r) {
                    int rr = mbase + m * 16 + (lane >> 4) * 4 + r;
                    int cc = nbase + n * 16 + (lane & 15);
                    long grow = obase + (row0 + rr) * 256 + c0 + cc;
                    int gcol = c0 + cc;
                    float v = acc[m][n][r] + bf2f(Z[grow]) + b0[gcol] + b1[gcol];
                    if (res) v += bf2f(res[grow]);
                    v = fmaxf(v, 0.f);
                    Out[grow] = f2bf(v);
                }
    };

    // ---- phase sequence (27 grid barriers) ----
    int tgt = 0;
    wg_phase(Xh, K1, 3, Whf, K1);
    gbar(bar, tgt += 256);
    agg_phase(first_b, first_b + 256, nullptr, Hn);
    for (int i = 0; i < 6; ++i) {
        const u16* W = Whm + (size_t)i * 4 * 65536;
        const float* bb = mid_b + (size_t)i * 1024;
        gbar(bar, tgt += 256);
        wg_phase(Hn, 256, 4, W, 256);
        gbar(bar, tgt += 256);
        agg_phase(bb, bb + 256, nullptr, On);
        gbar(bar, tgt += 256);
        wg_phase(On, 256, 4, W + 2 * 65536, 256);
        gbar(bar, tgt += 256);
        agg_phase(bb + 512, bb + 768, Hn, Hn);
    }
    gbar(bar, tgt += 256);
    wg_phase(Hn, 256, 4, Whl, 256);
    gbar(bar, tgt += 256);
    agg_phase(last_b, last_b + 256, nullptr, On);
}

// ---------------------------------------------------------------------------
// FC head: 8 lanes per node, shfl reduce.
// ---------------------------------------------------------------------------
__global__ __launch_bounds__(256) void k_fc(const u16* __restrict__ Hf,
                     const float* __restrict__ fcW, const float* __restrict__ fcb,
                     const float* __restrict__ base_point,
                     const float* __restrict__ mask,
                     float* __restrict__ out, float* __restrict__ G) {
    int t = threadIdx.x;
    int w = t >> 6, l = t & 63;
    int bn = blockIdx.x * 32 + w * 8 + (l >> 3);
    int kc = (l & 7) * 32;
    const u16* hr = Hf + (long)bn * SS + kc;
    float a0 = 0.f, a1 = 0.f;
    #pragma unroll
    for (int j = 0; j < 32; j += 8) {
        short8v v = *(const short8v*)(hr + j);
        #pragma unroll
        for (int jj = 0; jj < 8; ++jj) {
            float f = bf2f((u16)v[jj]);
            a0 += f * fcW[kc + j + jj];
            a1 += f * fcW[SS + kc + j + jj];
        }
    }
    #pragma unroll
    for (int off = 1; off < 8; off <<= 1) {
        a0 += __shfl_xor(a0, off);
        a1 += __shfl_xor(a1, off);
    }
    if ((l & 7) == 0) {
        a0 += fcb[0]; a1 += fcb[1];
        float m  = mask[bn];
        float p0 = base_point[bn * 2 + 0], p1 = base_point[bn * 2 + 1];
        float g0 = a0 * m, g1 = a1 * m;
        out[16 + bn * 2 + 0] = p0 + g0;
        out[16 + bn * 2 + 1] = p1 + g1;
        out[16 + BN * 2 + bn * 2 + 0] = a0;
        out[16 + BN * 2 + bn * 2 + 1] = a1;
        G[bn * 2 + 0] = g0;
        G[bn * 2 + 1] = g1;
    }
}

// ---------------------------------------------------------------------------
// AG = adj @ G (u8 fixed adj); one wave per output row
// ---------------------------------------------------------------------------
__global__ __launch_bounds__(256) void k_adjg(const u8* __restrict__ A8,
                                              const float* __restrict__ G,
                                              float* __restrict__ AG) {
    int w = threadIdx.x >> 6, lane = threadIdx.x & 63;
    long row = (long)blockIdx.x * 4 + w;
    int b = (int)(row >> 10);
    const u8* ar = A8 + ((long)b * NN + (row & 1023)) * NN;
    const float* Gb = G + (long)b * NN * 2;
    float s0 = 0.f, s1 = 0.f;
    int k0 = lane * 16;
    uint4 v = *(const uint4*)(ar + k0);
    unsigned arr[4] = {v.x, v.y, v.z, v.w};
    #pragma unroll
    for (int i2 = 0; i2 < 4; ++i2) {
        #pragma unroll
        for (int bs = 0; bs < 4; ++bs) {
            float a = (float)((arr[i2] >> (8 * bs)) & 0xffu);
            int k = k0 + i2 * 4 + bs;
            s0 += a * Gb[k * 2 + 0];
            s1 += a * Gb[k * 2 + 1];
        }
    }
    #pragma unroll
    for (int off = 32; off; off >>= 1) {
        s0 += __shfl_down(s0, off);
        s1 += __shfl_down(s1, off);
    }
    if (lane == 0) {
        AG[row * 2 + 0] = s0 * 0x1p-18f;
        AG[row * 2 + 1] = s1 * 0x1p-18f;
    }
}

// ---------------------------------------------------------------------------
// energy
// ---------------------------------------------------------------------------
__global__ __launch_bounds__(256) void k_energy(const float* __restrict__ G,
                                                const float* __restrict__ AG,
                                                float* __restrict__ out) {
    __shared__ float red[256];
    int b = blockIdx.x, t = threadIdx.x;
    float s = 0.f;
    for (int n = t; n < NN; n += 256) {
        int bn = b * NN + n;
        float dx = G[bn * 2 + 0] - AG[bn * 2 + 0];
        float dy = G[bn * 2 + 1] - AG[bn * 2 + 1];
        s += sqrtf(dx * dx + dy * dy + 1e-10f);
    }
    red[t] = s;
    __syncthreads();
    for (int off = 128; off > 0; off >>= 1) {
        if (t < off) red[t] += red[t + off];
        __syncthreads();
    }
    if (t == 0) out[b] = red[0] / (float)NN;
}

// ---------------------------------------------------------------------------
extern "C" void kernel_launch(void* const* d_in, const int* in_sizes, int n_in,
                              void* d_out, int out_size, void* d_ws, size_t ws_size,
                              hipStream_t stream) {
    const float* features   = (const float*)d_in[0];
    const float* base_point = (const float*)d_in[1];
    const float* adj        = (const float*)d_in[2];
    const float* mask       = (const float*)d_in[3];
    const float* first_W    = (const float*)d_in[4];
    const float* first_b    = (const float*)d_in[5];
    const float* mid_W      = (const float*)d_in[6];
    const float* mid_b      = (const float*)d_in[7];
    const float* last_W     = (const float*)d_in[8];
    const float* last_b     = (const float*)d_in[9];
    const float* fc_W       = (const float*)d_in[10];
    const float* fc_b       = (const float*)d_in[11];
    float* out = (float*)d_out;
    char* p = (char*)d_ws;

    // Region 0 (67.1 MB): featT first; then reused for adjq / Z / Hn / On / G / AG / bar.
    u16*  featT = (u16*)p;
    u8*   adjq  = (u8*)p;                                    // 16.78 MB
    u16*  Z     = (u16*)(p + 16777216);                      //  8.39 MB
    u16*  Hn    = (u16*)(p + 16777216 + 8388608);            //  8.39 MB
    u16*  On    = (u16*)(p + 16777216 + 2 * 8388608);        //  8.39 MB
    float* G    = (float*)(p + 16777216 + 3 * 8388608);      //  0.13 MB
    float* AG   = G + (size_t)BN * 2;                        //  0.13 MB
    int*  bar   = (int*)(AG + (size_t)BN * 2);               //  4 B
    p += (size_t)BB * 16384 * 128 * 2;                       // 67108864

    u16* Xh  = (u16*)p;  p += (size_t)BN * K1 * 2;
    u16* YT  = (u16*)p;  p += (size_t)BB * 256 * 1024 * 2;
    u16* Whf = (u16*)p;  p += (size_t)2 * 256 * K1 * 2;
    u16* Whm = (u16*)p;  p += (size_t)6 * 4 * 256 * 256 * 2;
    u16* Whl = (u16*)p;  p += (size_t)2 * 256 * 256 * 2;

    k_ftrans<<<dim3(128, 16), 256, 0, stream>>>(features, featT);
    k_interp<<<BN / 4, 256, 0, stream>>>(featT, base_point, Xh);

    k_castA8<<<2048, 256, 0, stream>>>(adj, adjq, (long)BB * NN * NN / 4, bar);
    k_cast4<<<256, 256, 0, stream>>>(mid_W, Whm, (long)6 * 4 * 256 * 256 / 4);
    k_cast4<<<64, 256, 0, stream>>>(last_W, Whl, (long)2 * 256 * 256 / 4);
    k_castW1<<<(2 * 256 * K1 + 255) / 256, 256, 0, stream>>>(first_W, Whf);

    k_mega<<<256, 512, 0, stream>>>(adjq, Xh, Whf, Whm, Whl,
                                    first_b, mid_b, last_b,
                                    Z, YT, Hn, On, bar);

    // head + energy
    k_fc<<<BN / 32, 256, 0, stream>>>(On, fc_W, fc_b, base_point, mask, out, G);
    k_adjg<<<BN / 4, 256, 0, stream>>>(adjq, G, AG);
    k_energy<<<BB, 256, 0, stream>>>(G, AG, out);
}

// Round 15
// 543.930 us; speedup vs baseline: 2.1280x; 2.1280x over previous
//
#include <hip/hip_runtime.h>
#include <cmath>

#define BB 16
#define CC 128
#define HH 128
#define WW 128
#define NN 1024
#define SS 256
#define BN (BB*NN)
#define K1 192            // first-layer K padded: 130 -> 192 (3 x 64)

typedef short short8v __attribute__((ext_vector_type(8)));
typedef float f32x4 __attribute__((ext_vector_type(4)));
typedef unsigned short u16;
typedef unsigned char u8;

__device__ __forceinline__ u16 f2bf(float f) {
    unsigned u = __builtin_bit_cast(unsigned, f);
    unsigned r = (u + 0x7FFFu + ((u >> 16) & 1u)) >> 16;
    return (u16)r;
}
__device__ __forceinline__ float bf2f(u16 h) {
    unsigned u = ((unsigned)h) << 16;
    return __builtin_bit_cast(float, u);
}

// ---------------------------------------------------------------------------
// merged preprocessing: one launch, block-role partitioned.
//  [0,2048)        : adj f32 -> u8 fixed (q = round(adj*2^18))
//  [2048,4096)     : features -> featT bf16 tiled transpose
//  [4096,4352)     : mid_W  -> bf16
//  [4352,4416)     : last_W -> bf16
//  [4416,4800)     : first_W -> bf16 [2][256][192] zero-padded
// ---------------------------------------------------------------------------
__global__ __launch_bounds__(256) void k_prep(
    const float* __restrict__ adj,   u8*  __restrict__ adjq,
    const float* __restrict__ feat,  u16* __restrict__ featT,
    const float* __restrict__ mid_W, u16* __restrict__ Whm,
    const float* __restrict__ last_W,u16* __restrict__ Whl,
    const float* __restrict__ first_W, u16* __restrict__ Whf) {

    int bid = blockIdx.x;
    int t = threadIdx.x;

    if (bid < 2048) {                          // castA8
        long n4 = (long)BB * NN * NN / 4;
        long i = (long)bid * 256 + t;
        long st = 2048L * 256;
        for (; i < n4; i += st) {
            float4 v = ((const float4*)adj)[i];
            uchar4 o;
            o.x = (u8)min(255, (int)(v.x * 262144.f + 0.5f));
            o.y = (u8)min(255, (int)(v.y * 262144.f + 0.5f));
            o.z = (u8)min(255, (int)(v.z * 262144.f + 0.5f));
            o.w = (u8)min(255, (int)(v.w * 262144.f + 0.5f));
            ((uchar4*)adjq)[i] = o;
        }
    } else if (bid < 4096) {                   // ftrans
        __shared__ u16 T[128][132];
        int idx = bid - 2048;
        int b = idx >> 7, hw0 = (idx & 127) * 128;
        const float* fb = feat + (long)b * CC * (HH * WW);
        #pragma unroll
        for (int p = 0; p < 16; ++p) {
            int c = p * 8 + (t >> 5);
            int x = (t & 31) * 4;
            float4 v = *(const float4*)(fb + (long)c * (HH * WW) + hw0 + x);
            T[x + 0][c] = f2bf(v.x); T[x + 1][c] = f2bf(v.y);
            T[x + 2][c] = f2bf(v.z); T[x + 3][c] = f2bf(v.w);
        }
        __syncthreads();
        #pragma unroll
        for (int p = 0; p < 8; ++p) {
            int hw = p * 16 + (t >> 4);
            int c8 = (t & 15) * 8;
            short8v v = *(const short8v*)&T[hw][c8];
            *(short8v*)(featT + ((long)b * 16384 + hw0 + hw) * 128 + c8) = v;
        }
    } else if (bid < 4352) {                   // cast mid_W
        long n4 = (long)6 * 4 * 256 * 256 / 4;
        long i = (long)(bid - 4096) * 256 + t;
        long st = 256L * 256;
        for (; i < n4; i += st) {
            float4 v = ((const float4*)mid_W)[i];
            ushort4 o;
            o.x = f2bf(v.x); o.y = f2bf(v.y); o.z = f2bf(v.z); o.w = f2bf(v.w);
            ((ushort4*)Whm)[i] = o;
        }
    } else if (bid < 4416) {                   // cast last_W
        long n4 = (long)2 * 256 * 256 / 4;
        long i = (long)(bid - 4352) * 256 + t;
        long st = 64L * 256;
        for (; i < n4; i += st) {
            float4 v = ((const float4*)last_W)[i];
            ushort4 o;
            o.x = f2bf(v.x); o.y = f2bf(v.y); o.z = f2bf(v.z); o.w = f2bf(v.w);
            ((ushort4*)Whl)[i] = o;
        }
    } else {                                   // castW1 (first_W zero-padded)
        int idx = (bid - 4416) * 256 + t;
        if (idx < 2 * 256 * K1) {
            int k = idx % K1, r = idx / K1;
            Whf[idx] = (k < 130) ? f2bf(first_W[r * 130 + k]) : (u16)0;
        }
    }
}

// ---------------------------------------------------------------------------
// interp: wave per node; lane = (corner<<4)|chunk. writes Xh [BN][192]
// ---------------------------------------------------------------------------
__global__ __launch_bounds__(256) void k_interp(const u16* __restrict__ featT,
                                                const float* __restrict__ base_point,
                                                u16* __restrict__ Xh) {
    int t = threadIdx.x;
    int lane = t & 63, w = t >> 6;
    int bn = blockIdx.x * 4 + w;
    int b = bn >> 10;
    float px = base_point[bn * 2 + 0];
    float py = base_point[bn * 2 + 1];
    float Xs = px * WW, Ys = py * HH;
    float X0f = floorf(Xs), Y0f = floorf(Ys);
    float fx = Xs - X0f, fy = Ys - Y0f;
    int x0 = min(max((int)X0f, 0), WW - 1);
    int x1 = min(max((int)(X0f + 1.f), 0), WW - 1);
    int y0 = min(max((int)Y0f, 0), HH - 1);
    int y1 = min(max((int)(Y0f + 1.f), 0), HH - 1);
    int corner = lane >> 4, chunk = lane & 15;
    int xi = (corner & 2) ? x1 : x0;
    int yi = (corner & 1) ? y1 : y0;
    float wgt = ((corner & 2) ? fx : 1.f - fx) * ((corner & 1) ? fy : 1.f - fy);
    const u16* fp = featT + ((long)b * 16384 + yi * WW + xi) * 128 + chunk * 8;
    short8v v = *(const short8v*)fp;
    float a[8];
    #pragma unroll
    for (int j = 0; j < 8; ++j) a[j] = wgt * bf2f((u16)v[j]);
    #pragma unroll
    for (int j = 0; j < 8; ++j) {
        a[j] += __shfl_xor(a[j], 16);
        a[j] += __shfl_xor(a[j], 32);
    }
    if (lane < 16) {
        short8v o;
        #pragma unroll
        for (int j = 0; j < 8; ++j) o[j] = (short)f2bf(a[j]);
        *(short8v*)(Xh + (long)bn * K1 + chunk * 8) = o;
    } else if (lane < 24) {
        short8v o = {};
        if (lane == 16) { o[0] = (short)f2bf(px); o[1] = (short)f2bf(py); }
        *(short8v*)(Xh + (long)bn * K1 + 128 + (lane - 16) * 8) = o;
    }
}

// ---------------------------------------------------------------------------
// Weight GEMM: [Z|Y] = A @ W^T, W rows 0..255 -> Z (normal), 256..511 -> Y
// written TRANSPOSED into YT [16][256][1024]. Raw (no bias/relu).
// 8 waves, 128x128 tile, BK=64, 3-stage 96KB, vmcnt(4).
// grid (4,128): swizzle keeps the 4 col-blocks of one row-slice on one XCD.
// ---------------------------------------------------------------------------
__global__ __launch_bounds__(512) void k_wg(
    const u16* __restrict__ A, int lda, int nK,
    const u16* __restrict__ W, int ldw,
    u16* __restrict__ Z,            // [16384][256] bf16
    u16* __restrict__ YT) {         // [16][256][1024] bf16

    __shared__ u16 lds[49152];

    int t = threadIdx.x;
    int lane = t & 63, w = t >> 6;
    int wr = w >> 1, wc = w & 1;

    int h = blockIdx.x + 4 * blockIdx.y;           // 512 blocks
    int bx = (h >> 3) & 3;
    int by = (h & 7) | ((h >> 5) << 3);
    int c0 = bx * 128;
    long row0 = (long)by * 128;

    f32x4 acc[2][4] = {};

    auto stage = [&](int s, int bufbase) {
        int kt = s * 64;
        u16* As = lds + bufbase;
        u16* Bs = lds + bufbase + 8192;
        #pragma unroll
        for (int q = 0; q < 2; ++q) {
            int rb = w * 16 + q * 8;
            int row = rb + (lane >> 3);
            int koff = kt + (((lane & 7) ^ (row & 7)) << 3);
            __builtin_amdgcn_global_load_lds(
                (const __attribute__((address_space(1))) void*)(A + (row0 + row) * lda + koff),
                (__attribute__((address_space(3))) void*)(As + rb * 64), 16, 0, 0);
            __builtin_amdgcn_global_load_lds(
                (const __attribute__((address_space(1))) void*)(W + (long)(c0 + row) * ldw + koff),
                (__attribute__((address_space(3))) void*)(Bs + rb * 64), 16, 0, 0);
        }
    };

    stage(0, 0);
    if (nK > 1) stage(1, 16384);

    int curb = 0, stb = 32768;
    for (int s = 0; s < nK; ++s) {
        if (s + 1 < nK) { asm volatile("s_waitcnt vmcnt(4)" ::: "memory"); }
        else            { asm volatile("s_waitcnt vmcnt(0)" ::: "memory"); }
        __builtin_amdgcn_sched_barrier(0);
        __builtin_amdgcn_s_barrier();
        if (s + 2 < nK) stage(s + 2, stb);
        const u16* As = lds + curb;
        const u16* Bs = lds + curb + 8192;
        #pragma unroll
        for (int kk = 0; kk < 2; ++kk) {
            short8v a[2], bfr[4];
            #pragma unroll
            for (int m = 0; m < 2; ++m) {
                int row = wr * 32 + m * 16 + (lane & 15);
                int sl = (kk * 4 + (lane >> 4)) ^ (row & 7);
                a[m] = *(const short8v*)(As + row * 64 + sl * 8);
            }
            #pragma unroll
            for (int n = 0; n < 4; ++n) {
                int row = wc * 64 + n * 16 + (lane & 15);
                int sl = (kk * 4 + (lane >> 4)) ^ (row & 7);
                bfr[n] = *(const short8v*)(Bs + row * 64 + sl * 8);
            }
            #pragma unroll
            for (int m = 0; m < 2; ++m)
                #pragma unroll
                for (int n = 0; n < 4; ++n)
                    acc[m][n] = __builtin_amdgcn_mfma_f32_16x16x32_bf16(
                        a[m], bfr[n], acc[m][n], 0, 0, 0);
        }
        curb += 16384; if (curb == 49152) curb = 0;
        stb  += 16384; if (stb  == 49152) stb  = 0;
    }

    int mbase = wr * 32, nbase = wc * 64;
    if (c0 < 256) {
        #pragma unroll
        for (int m = 0; m < 2; ++m)
            #pragma unroll
            for (int n = 0; n < 4; ++n)
                #pragma unroll
                for (int r = 0; r < 4; ++r) {
                    int rr = mbase + m * 16 + (lane >> 4) * 4 + r;
                    int cc = nbase + n * 16 + (lane & 15);
                    Z[(row0 + rr) * 256 + c0 + cc] = f2bf(acc[m][n][r]);
                }
    } else {
        u16 (*T)[136] = (u16(*)[136])lds;
        __syncthreads();
        #pragma unroll
        for (int m = 0; m < 2; ++m)
            #pragma unroll
            for (int n = 0; n < 4; ++n)
                #pragma unroll
                for (int r = 0; r < 4; ++r) {
                    int rr = mbase + m * 16 + (lane >> 4) * 4 + r;
                    int cc = nbase + n * 16 + (lane & 15);
                    T[cc][rr] = f2bf(acc[m][n][r]);
                }
        __syncthreads();
        int bb2 = (int)(row0 >> 10);
        long nodeBase = row0 & 1023;
        int fbase = c0 - 256;
        #pragma unroll
        for (int p = 0; p < 4; ++p) {
            int c = p * 32 + (t >> 4);
            int moff = (t & 15) * 8;
            short8v vv = *(const short8v*)(&T[c][moff]);
            *(short8v*)(YT + ((long)bb2 * 256 + fbase + c) * 1024 + nodeBase + moff) = vv;
        }
    }
}

// ---------------------------------------------------------------------------
// out = relu( Z + adj(u8 fixed)@Y + b0 + b1 [+res] ).  u8-A via
// global_load_lds, VALU dequant; fused epilogue. 8 waves, 128x128, BK=64,
// 3-stage 72KB, vmcnt(3). Batch->XCD pin. grid 256 x 512.
// ---------------------------------------------------------------------------
__global__ __launch_bounds__(512) void k_agg2(
    const u8* __restrict__ A8,
    const u16* __restrict__ YT,
    const u16* __restrict__ Z,
    const float* __restrict__ b0, const float* __restrict__ b1,
    const u16* __restrict__ res,
    u16* __restrict__ Out) {

    __shared__ u16 lds[36864];
    const int BUF = 12288;

    int t = threadIdx.x;
    int lane = t & 63, w = t >> 6;
    int wr = w >> 1, wc = w & 1;

    int h = blockIdx.x;
    int bz = h & 15, tt = h >> 4;
    int bx = tt & 1, by = tt >> 1;
    long row0 = (long)by * 128;
    int c0 = bx * 128;

    const u8*  Ap = A8 + (long)bz * NN * NN;
    const u16* Bp = YT + (long)bz * 256 * 1024;
    long obase = (long)bz * NN * 256;

    f32x4 acc[2][4] = {};

    int ar = t >> 2, ac = t & 3;
    int ac_src = ac ^ ((ar & 7) >> 1);

    auto stage = [&](int s, int bufbase) {
        int kt = s * 64;
        u8*  As = (u8*)(lds + bufbase);
        u16* Bs = lds + bufbase + 4096;
        __builtin_amdgcn_global_load_lds(
            (const __attribute__((address_space(1))) void*)(Ap + (row0 + ar) * NN + kt + ac_src * 16),
            (__attribute__((address_space(3))) void*)(As + ar * 64 + ac * 16), 16, 0, 0);
        #pragma unroll
        for (int q = 0; q < 2; ++q) {
            int rb = w * 16 + q * 8;
            int row = rb + (lane >> 3);
            int koff = kt + (((lane & 7) ^ (row & 7)) << 3);
            __builtin_amdgcn_global_load_lds(
                (const __attribute__((address_space(1))) void*)(Bp + (long)(c0 + row) * NN + koff),
                (__attribute__((address_space(3))) void*)(Bs + rb * 64), 16, 0, 0);
        }
    };

    stage(0, 0);
    stage(1, BUF);

    int curb = 0, stb = 2 * BUF;
    for (int s = 0; s < 16; ++s) {
        if (s < 15) { asm volatile("s_waitcnt vmcnt(3)" ::: "memory"); }
        else        { asm volatile("s_waitcnt vmcnt(0)" ::: "memory"); }
        __builtin_amdgcn_sched_barrier(0);
        __builtin_amdgcn_s_barrier();
        if (s + 2 < 16) stage(s + 2, stb);
        const u8*  As = (const u8*)(lds + curb);
        const u16* Bs = lds + curb + 4096;
        #pragma unroll
        for (int kk = 0; kk < 2; ++kk) {
            short8v a[2], bfr[4];
            #pragma unroll
            for (int m = 0; m < 2; ++m) {
                int row = wr * 32 + m * 16 + (lane & 15);
                int sfull = kk * 4 + (lane >> 4);
                int chunk = (sfull >> 1) ^ ((row & 7) >> 1);
                const unsigned* pq = (const unsigned*)(As + row * 64 + chunk * 16 + (sfull & 1) * 8);
                unsigned q0 = pq[0], q1 = pq[1];
                unsigned od[4];
                {
                    float f0 = (float)(q0 & 0xffu)         * 0x1p-18f;
                    float f1 = (float)((q0 >> 8) & 0xffu)  * 0x1p-18f;
                    float f2 = (float)((q0 >> 16) & 0xffu) * 0x1p-18f;
                    float f3 = (float)(q0 >> 24)           * 0x1p-18f;
                    od[0] = __builtin_amdgcn_perm(
                        __builtin_bit_cast(unsigned, f1), __builtin_bit_cast(unsigned, f0), 0x07060302u);
                    od[1] = __builtin_amdgcn_perm(
                        __builtin_bit_cast(unsigned, f3), __builtin_bit_cast(unsigned, f2), 0x07060302u);
                }
                {
                    float f0 = (float)(q1 & 0xffu)         * 0x1p-18f;
                    float f1 = (float)((q1 >> 8) & 0xffu)  * 0x1p-18f;
                    float f2 = (float)((q1 >> 16) & 0xffu) * 0x1p-18f;
                    float f3 = (float)(q1 >> 24)           * 0x1p-18f;
                    od[2] = __builtin_amdgcn_perm(
                        __builtin_bit_cast(unsigned, f1), __builtin_bit_cast(unsigned, f0), 0x07060302u);
                    od[3] = __builtin_amdgcn_perm(
                        __builtin_bit_cast(unsigned, f3), __builtin_bit_cast(unsigned, f2), 0x07060302u);
                }
                a[m] = __builtin_bit_cast(short8v, *(uint4*)od);
            }
            #pragma unroll
            for (int n = 0; n < 4; ++n) {
                int row = wc * 64 + n * 16 + (lane & 15);
                int sl = (kk * 4 + (lane >> 4)) ^ (row & 7);
                bfr[n] = *(const short8v*)(Bs + row * 64 + sl * 8);
            }
            #pragma unroll
            for (int m = 0; m < 2; ++m)
                #pragma unroll
                for (int n = 0; n < 4; ++n)
                    acc[m][n] = __builtin_amdgcn_mfma_f32_16x16x32_bf16(
                        a[m], bfr[n], acc[m][n], 0, 0, 0);
        }
        curb += BUF; if (curb == 3 * BUF) curb = 0;
        stb  += BUF; if (stb  == 3 * BUF) stb  = 0;
    }

    int mbase = wr * 32, nbase = wc * 64;
    #pragma unroll
    for (int m = 0; m < 2; ++m)
        #pragma unroll
        for (int n = 0; n < 4; ++n)
            #pragma unroll
            for (int r = 0; r < 4; ++r) {
                int rr = mbase + m * 16 + (lane >> 4) * 4 + r;
                int cc = nbase + n * 16 + (lane & 15);
                long grow = obase + (row0 + rr) * 256 + c0 + cc;
                int gcol = c0 + cc;
                float v = acc[m][n][r] + bf2f(Z[grow]) + b0[gcol] + b1[gcol];
                if (res) v += bf2f(res[grow]);
                v = fmaxf(v, 0.f);
                Out[grow] = f2bf(v);
            }
}

// ---------------------------------------------------------------------------
// FC head: 8 lanes per node, shfl reduce.
// ---------------------------------------------------------------------------
__global__ __launch_bounds__(256) void k_fc(const u16* __restrict__ Hf,
                     const float* __restrict__ fcW, const float* __restrict__ fcb,
                     const float* __restrict__ base_point,
                     const float* __restrict__ mask,
                     float* __restrict__ out, float* __restrict__ G) {
    int t = threadIdx.x;
    int w = t >> 6, l = t & 63;
    int bn = blockIdx.x * 32 + w * 8 + (l >> 3);
    int kc = (l & 7) * 32;
    const u16* hr = Hf + (long)bn * SS + kc;
    float a0 = 0.f, a1 = 0.f;
    #pragma unroll
    for (int j = 0; j < 32; j += 8) {
        short8v v = *(const short8v*)(hr + j);
        #pragma unroll
        for (int jj = 0; jj < 8; ++jj) {
            float f = bf2f((u16)v[jj]);
            a0 += f * fcW[kc + j + jj];
            a1 += f * fcW[SS + kc + j + jj];
        }
    }
    #pragma unroll
    for (int off = 1; off < 8; off <<= 1) {
        a0 += __shfl_xor(a0, off);
        a1 += __shfl_xor(a1, off);
    }
    if ((l & 7) == 0) {
        a0 += fcb[0]; a1 += fcb[1];
        float m  = mask[bn];
        float p0 = base_point[bn * 2 + 0], p1 = base_point[bn * 2 + 1];
        float g0 = a0 * m, g1 = a1 * m;
        out[16 + bn * 2 + 0] = p0 + g0;
        out[16 + bn * 2 + 1] = p1 + g1;
        out[16 + BN * 2 + bn * 2 + 0] = a0;
        out[16 + BN * 2 + bn * 2 + 1] = a1;
        G[bn * 2 + 0] = g0;
        G[bn * 2 + 1] = g1;
    }
}

// ---------------------------------------------------------------------------
// AG = adj @ G (u8 fixed adj); one wave per output row
// ---------------------------------------------------------------------------
__global__ __launch_bounds__(256) void k_adjg(const u8* __restrict__ A8,
                                              const float* __restrict__ G,
                                              float* __restrict__ AG) {
    int w = threadIdx.x >> 6, lane = threadIdx.x & 63;
    long row = (long)blockIdx.x * 4 + w;
    int b = (int)(row >> 10);
    const u8* ar = A8 + ((long)b * NN + (row & 1023)) * NN;
    const float* Gb = G + (long)b * NN * 2;
    float s0 = 0.f, s1 = 0.f;
    int k0 = lane * 16;
    uint4 v = *(const uint4*)(ar + k0);
    unsigned arr[4] = {v.x, v.y, v.z, v.w};
    #pragma unroll
    for (int i2 = 0; i2 < 4; ++i2) {
        #pragma unroll
        for (int bs = 0; bs < 4; ++bs) {
            float a = (float)((arr[i2] >> (8 * bs)) & 0xffu);
            int k = k0 + i2 * 4 + bs;
            s0 += a * Gb[k * 2 + 0];
            s1 += a * Gb[k * 2 + 1];
        }
    }
    #pragma unroll
    for (int off = 32; off; off >>= 1) {
        s0 += __shfl_down(s0, off);
        s1 += __shfl_down(s1, off);
    }
    if (lane == 0) {
        AG[row * 2 + 0] = s0 * 0x1p-18f;
        AG[row * 2 + 1] = s1 * 0x1p-18f;
    }
}

// ---------------------------------------------------------------------------
// energy
// ---------------------------------------------------------------------------
__global__ __launch_bounds__(256) void k_energy(const float* __restrict__ G,
                                                const float* __restrict__ AG,
                                                float* __restrict__ out) {
    __shared__ float red[256];
    int b = blockIdx.x, t = threadIdx.x;
    float s = 0.f;
    for (int n = t; n < NN; n += 256) {
        int bn = b * NN + n;
        float dx = G[bn * 2 + 0] - AG[bn * 2 + 0];
        float dy = G[bn * 2 + 1] - AG[bn * 2 + 1];
        s += sqrtf(dx * dx + dy * dy + 1e-10f);
    }
    red[t] = s;
    __syncthreads();
    for (int off = 128; off > 0; off >>= 1) {
        if (t < off) red[t] += red[t + off];
        __syncthreads();
    }
    if (t == 0) out[b] = red[0] / (float)NN;
}

// ---------------------------------------------------------------------------
extern "C" void kernel_launch(void* const* d_in, const int* in_sizes, int n_in,
                              void* d_out, int out_size, void* d_ws, size_t ws_size,
                              hipStream_t stream) {
    const float* features   = (const float*)d_in[0];
    const float* base_point = (const float*)d_in[1];
    const float* adj        = (const float*)d_in[2];
    const float* mask       = (const float*)d_in[3];
    const float* first_W    = (const float*)d_in[4];
    const float* first_b    = (const float*)d_in[5];
    const float* mid_W      = (const float*)d_in[6];
    const float* mid_b      = (const float*)d_in[7];
    const float* last_W     = (const float*)d_in[8];
    const float* last_b     = (const float*)d_in[9];
    const float* fc_W       = (const float*)d_in[10];
    const float* fc_b       = (const float*)d_in[11];
    float* out = (float*)d_out;
    char* p = (char*)d_ws;

    // Region 0 (67.1 MB): featT first; then reused for adjq / Z / Hn / On / G / AG.
    u16*  featT = (u16*)p;
    u8*   adjq  = (u8*)p;                                    // 16.78 MB
    u16*  Z     = (u16*)(p + 16777216);                      //  8.39 MB
    u16*  Hn    = (u16*)(p + 16777216 + 8388608);            //  8.39 MB
    u16*  On    = (u16*)(p + 16777216 + 2 * 8388608);        //  8.39 MB
    float* G    = (float*)(p + 16777216 + 3 * 8388608);      //  0.13 MB
    float* AG   = G + (size_t)BN * 2;                        //  0.13 MB
    p += (size_t)BB * 16384 * 128 * 2;                       // 67108864

    u16* Xh  = (u16*)p;  p += (size_t)BN * K1 * 2;
    u16* YT  = (u16*)p;  p += (size_t)BB * 256 * 1024 * 2;
    u16* Whf = (u16*)p;  p += (size_t)2 * 256 * K1 * 2;
    u16* Whm = (u16*)p;  p += (size_t)6 * 4 * 256 * 256 * 2;
    u16* Whl = (u16*)p;  p += (size_t)2 * 256 * 256 * 2;

    // NOTE: featT aliases adjq/Z/... — k_prep writes featT (region head) AND
    // adjq would collide. Keep adjq in its own slot: featT occupies the whole
    // 67MB region; adjq etc. are reused only AFTER interp consumes featT.
    // But k_prep writes adjq too -> must NOT overlap. Place adjq AFTER the
    // featT region instead (it fits: ws is large).
    u8* adjq2 = (u8*)p;  p += (size_t)BB * NN * NN;          // 16.78 MB (non-aliased)

    k_prep<<<4800, 256, 0, stream>>>(adj, adjq2, features, featT,
                                     mid_W, Whm, last_W, Whl, first_W, Whf);
    k_interp<<<BN / 4, 256, 0, stream>>>(featT, base_point, Xh);

    dim3 gWg(4, 128), blk(512);

    // first layer: [Z|Y] = Xh @ [W0|W1]^T ; Hn = relu(Z + adj@Y + b)
    k_wg<<<gWg, blk, 0, stream>>>(Xh, K1, 3, Whf, K1, Z, YT);
    k_agg2<<<256, blk, 0, stream>>>(adjq2, YT, Z, first_b, first_b + 256, nullptr, Hn);

    for (int i = 0; i < 6; ++i) {
        const u16* W = Whm + (size_t)i * 4 * 256 * 256;
        const float* bb = mid_b + (size_t)i * 4 * 256;
        k_wg<<<gWg, blk, 0, stream>>>(Hn, 256, 4, W, 256, Z, YT);
        k_agg2<<<256, blk, 0, stream>>>(adjq2, YT, Z, bb, bb + 256, nullptr, On);
        k_wg<<<gWg, blk, 0, stream>>>(On, 256, 4, W + 2 * 65536, 256, Z, YT);
        k_agg2<<<256, blk, 0, stream>>>(adjq2, YT, Z, bb + 512, bb + 768, Hn, Hn);
    }

    // last layer
    k_wg<<<gWg, blk, 0, stream>>>(Hn, 256, 4, Whl, 256, Z, YT);
    k_agg2<<<256, blk, 0, stream>>>(adjq2, YT, Z, last_b, last_b + 256, nullptr, On);

    // head + energy
    k_fc<<<BN / 32, 256, 0, stream>>>(On, fc_W, fc_b, base_point, mask, out, G);
    k_adjg<<<BN / 4, 256, 0, stream>>>(adjq2, G, AG);
    k_energy<<<BB, 256, 0, stream>>>(G, AG, out);
}

// Round 16
// 542.760 us; speedup vs baseline: 2.1326x; 1.0022x over previous
//
#include <hip/hip_runtime.h>
#include <cmath>

#define BB 16
#define CC 128
#define HH 128
#define WW 128
#define NN 1024
#define SS 256
#define BN (BB*NN)
#define K1 192            // first-layer K padded: 130 -> 192 (3 x 64)

typedef short short8v __attribute__((ext_vector_type(8)));
typedef float f32x4 __attribute__((ext_vector_type(4)));
typedef unsigned short u16;
typedef unsigned char u8;

__device__ __forceinline__ u16 f2bf(float f) {
    unsigned u = __builtin_bit_cast(unsigned, f);
    unsigned r = (u + 0x7FFFu + ((u >> 16) & 1u)) >> 16;
    return (u16)r;
}
__device__ __forceinline__ float bf2f(u16 h) {
    unsigned u = ((unsigned)h) << 16;
    return __builtin_bit_cast(float, u);
}

// ---------------------------------------------------------------------------
// merged preprocessing: one launch, block-role partitioned.
//  [0,2048)        : adj f32 -> u8 fixed (q = round(adj*2^18))
//  [2048,4096)     : features -> featT bf16 tiled transpose (conflict-free)
//  [4096,4352)     : mid_W  -> bf16
//  [4352,4416)     : last_W -> bf16
//  [4416,4800)     : first_W -> bf16 [2][256][192] zero-padded
// ---------------------------------------------------------------------------
__global__ __launch_bounds__(256) void k_prep(
    const float* __restrict__ adj,   u8*  __restrict__ adjq,
    const float* __restrict__ feat,  u16* __restrict__ featT,
    const float* __restrict__ mid_W, u16* __restrict__ Whm,
    const float* __restrict__ last_W,u16* __restrict__ Whl,
    const float* __restrict__ first_W, u16* __restrict__ Whf) {

    int bid = blockIdx.x;
    int t = threadIdx.x;

    if (bid < 2048) {                          // castA8
        long n4 = (long)BB * NN * NN / 4;
        long i = (long)bid * 256 + t;
        long st = 2048L * 256;
        for (; i < n4; i += st) {
            float4 v = ((const float4*)adj)[i];
            uchar4 o;
            o.x = (u8)min(255, (int)(v.x * 262144.f + 0.5f));
            o.y = (u8)min(255, (int)(v.y * 262144.f + 0.5f));
            o.z = (u8)min(255, (int)(v.z * 262144.f + 0.5f));
            o.w = (u8)min(255, (int)(v.w * 262144.f + 0.5f));
            ((uchar4*)adjq)[i] = o;
        }
    } else if (bid < 4096) {                   // ftrans, tile [c][hw] stride 129
        __shared__ u16 T[128][129];
        int idx = bid - 2048;
        int b = idx >> 7, hw0 = (idx & 127) * 128;
        const float* fb = feat + (long)b * CC * (HH * WW);
        #pragma unroll
        for (int p = 0; p < 16; ++p) {
            int c = p * 8 + (t >> 5);
            int x = (t & 31) * 4;
            float4 v = *(const float4*)(fb + (long)c * (HH * WW) + hw0 + x);
            T[c][x + 0] = f2bf(v.x); T[c][x + 1] = f2bf(v.y);
            T[c][x + 2] = f2bf(v.z); T[c][x + 3] = f2bf(v.w);
        }
        __syncthreads();
        #pragma unroll
        for (int p = 0; p < 8; ++p) {
            int hw = (t >> 4) + p * 16;
            int c8 = (t & 15) * 8;
            short8v o;
            #pragma unroll
            for (int j = 0; j < 8; ++j) o[j] = (short)T[c8 + j][hw];
            *(short8v*)(featT + ((long)b * 16384 + hw0 + hw) * 128 + c8) = o;
        }
    } else if (bid < 4352) {                   // cast mid_W
        long n4 = (long)6 * 4 * 256 * 256 / 4;
        long i = (long)(bid - 4096) * 256 + t;
        long st = 256L * 256;
        for (; i < n4; i += st) {
            float4 v = ((const float4*)mid_W)[i];
            ushort4 o;
            o.x = f2bf(v.x); o.y = f2bf(v.y); o.z = f2bf(v.z); o.w = f2bf(v.w);
            ((ushort4*)Whm)[i] = o;
        }
    } else if (bid < 4416) {                   // cast last_W
        long n4 = (long)2 * 256 * 256 / 4;
        long i = (long)(bid - 4352) * 256 + t;
        long st = 64L * 256;
        for (; i < n4; i += st) {
            float4 v = ((const float4*)last_W)[i];
            ushort4 o;
            o.x = f2bf(v.x); o.y = f2bf(v.y); o.z = f2bf(v.z); o.w = f2bf(v.w);
            ((ushort4*)Whl)[i] = o;
        }
    } else {                                   // castW1 (first_W zero-padded)
        int idx = (bid - 4416) * 256 + t;
        if (idx < 2 * 256 * K1) {
            int k = idx % K1, r = idx / K1;
            Whf[idx] = (k < 130) ? f2bf(first_W[r * 130 + k]) : (u16)0;
        }
    }
}

// ---------------------------------------------------------------------------
// interp: wave per node; lane = (corner<<4)|chunk. writes Xh [BN][192]
// ---------------------------------------------------------------------------
__global__ __launch_bounds__(256) void k_interp(const u16* __restrict__ featT,
                                                const float* __restrict__ base_point,
                                                u16* __restrict__ Xh) {
    int t = threadIdx.x;
    int lane = t & 63, w = t >> 6;
    int bn = blockIdx.x * 4 + w;
    int b = bn >> 10;
    float px = base_point[bn * 2 + 0];
    float py = base_point[bn * 2 + 1];
    float Xs = px * WW, Ys = py * HH;
    float X0f = floorf(Xs), Y0f = floorf(Ys);
    float fx = Xs - X0f, fy = Ys - Y0f;
    int x0 = min(max((int)X0f, 0), WW - 1);
    int x1 = min(max((int)(X0f + 1.f), 0), WW - 1);
    int y0 = min(max((int)Y0f, 0), HH - 1);
    int y1 = min(max((int)(Y0f + 1.f), 0), HH - 1);
    int corner = lane >> 4, chunk = lane & 15;
    int xi = (corner & 2) ? x1 : x0;
    int yi = (corner & 1) ? y1 : y0;
    float wgt = ((corner & 2) ? fx : 1.f - fx) * ((corner & 1) ? fy : 1.f - fy);
    const u16* fp = featT + ((long)b * 16384 + yi * WW + xi) * 128 + chunk * 8;
    short8v v = *(const short8v*)fp;
    float a[8];
    #pragma unroll
    for (int j = 0; j < 8; ++j) a[j] = wgt * bf2f((u16)v[j]);
    #pragma unroll
    for (int j = 0; j < 8; ++j) {
        a[j] += __shfl_xor(a[j], 16);
        a[j] += __shfl_xor(a[j], 32);
    }
    if (lane < 16) {
        short8v o;
        #pragma unroll
        for (int j = 0; j < 8; ++j) o[j] = (short)f2bf(a[j]);
        *(short8v*)(Xh + (long)bn * K1 + chunk * 8) = o;
    } else if (lane < 24) {
        short8v o = {};
        if (lane == 16) { o[0] = (short)f2bf(px); o[1] = (short)f2bf(py); }
        *(short8v*)(Xh + (long)bn * K1 + 128 + (lane - 16) * 8) = o;
    }
}

// ---------------------------------------------------------------------------
// Weight GEMM: [Z|Y] = A @ W^T, W rows 0..255 -> Z (normal), 256..511 -> Y
// written TRANSPOSED into YT [16][256][1024]. Raw (no bias/relu).
// 8 waves, 128x128 tile, BK=64, 3-stage 96KB, vmcnt(4).
// grid (4,128): swizzle keeps the 4 col-blocks of one row-slice on one XCD.
// ---------------------------------------------------------------------------
__global__ __launch_bounds__(512) void k_wg(
    const u16* __restrict__ A, int lda, int nK,
    const u16* __restrict__ W, int ldw,
    u16* __restrict__ Z,            // [16384][256] bf16
    u16* __restrict__ YT) {         // [16][256][1024] bf16

    __shared__ u16 lds[49152];

    int t = threadIdx.x;
    int lane = t & 63, w = t >> 6;
    int wr = w >> 1, wc = w & 1;

    int h = blockIdx.x + 4 * blockIdx.y;           // 512 blocks
    int bx = (h >> 3) & 3;
    int by = (h & 7) | ((h >> 5) << 3);
    int c0 = bx * 128;
    long row0 = (long)by * 128;

    f32x4 acc[2][4] = {};

    auto stage = [&](int s, int bufbase) {
        int kt = s * 64;
        u16* As = lds + bufbase;
        u16* Bs = lds + bufbase + 8192;
        #pragma unroll
        for (int q = 0; q < 2; ++q) {
            int rb = w * 16 + q * 8;
            int row = rb + (lane >> 3);
            int koff = kt + (((lane & 7) ^ (row & 7)) << 3);
            __builtin_amdgcn_global_load_lds(
                (const __attribute__((address_space(1))) void*)(A + (row0 + row) * lda + koff),
                (__attribute__((address_space(3))) void*)(As + rb * 64), 16, 0, 0);
            __builtin_amdgcn_global_load_lds(
                (const __attribute__((address_space(1))) void*)(W + (long)(c0 + row) * ldw + koff),
                (__attribute__((address_space(3))) void*)(Bs + rb * 64), 16, 0, 0);
        }
    };

    stage(0, 0);
    if (nK > 1) stage(1, 16384);

    int curb = 0, stb = 32768;
    for (int s = 0; s < nK; ++s) {
        if (s + 1 < nK) { asm volatile("s_waitcnt vmcnt(4)" ::: "memory"); }
        else            { asm volatile("s_waitcnt vmcnt(0)" ::: "memory"); }
        __builtin_amdgcn_sched_barrier(0);
        __builtin_amdgcn_s_barrier();
        if (s + 2 < nK) stage(s + 2, stb);
        const u16* As = lds + curb;
        const u16* Bs = lds + curb + 8192;
        #pragma unroll
        for (int kk = 0; kk < 2; ++kk) {
            short8v a[2], bfr[4];
            #pragma unroll
            for (int m = 0; m < 2; ++m) {
                int row = wr * 32 + m * 16 + (lane & 15);
                int sl = (kk * 4 + (lane >> 4)) ^ (row & 7);
                a[m] = *(const short8v*)(As + row * 64 + sl * 8);
            }
            #pragma unroll
            for (int n = 0; n < 4; ++n) {
                int row = wc * 64 + n * 16 + (lane & 15);
                int sl = (kk * 4 + (lane >> 4)) ^ (row & 7);
                bfr[n] = *(const short8v*)(Bs + row * 64 + sl * 8);
            }
            #pragma unroll
            for (int m = 0; m < 2; ++m)
                #pragma unroll
                for (int n = 0; n < 4; ++n)
                    acc[m][n] = __builtin_amdgcn_mfma_f32_16x16x32_bf16(
                        a[m], bfr[n], acc[m][n], 0, 0, 0);
        }
        curb += 16384; if (curb == 49152) curb = 0;
        stb  += 16384; if (stb  == 49152) stb  = 0;
    }

    int mbase = wr * 32, nbase = wc * 64;
    if (c0 < 256) {
        #pragma unroll
        for (int m = 0; m < 2; ++m)
            #pragma unroll
            for (int n = 0; n < 4; ++n)
                #pragma unroll
                for (int r = 0; r < 4; ++r) {
                    int rr = mbase + m * 16 + (lane >> 4) * 4 + r;
                    int cc = nbase + n * 16 + (lane & 15);
                    Z[(row0 + rr) * 256 + c0 + cc] = f2bf(acc[m][n][r]);
                }
    } else {
        u16 (*T)[136] = (u16(*)[136])lds;
        __syncthreads();
        #pragma unroll
        for (int m = 0; m < 2; ++m)
            #pragma unroll
            for (int n = 0; n < 4; ++n)
                #pragma unroll
                for (int r = 0; r < 4; ++r) {
                    int rr = mbase + m * 16 + (lane >> 4) * 4 + r;
                    int cc = nbase + n * 16 + (lane & 15);
                    T[cc][rr] = f2bf(acc[m][n][r]);
                }
        __syncthreads();
        int bb2 = (int)(row0 >> 10);
        long nodeBase = row0 & 1023;
        int fbase = c0 - 256;
        #pragma unroll
        for (int p = 0; p < 4; ++p) {
            int c = p * 32 + (t >> 4);
            int moff = (t & 15) * 8;
            short8v vv = *(const short8v*)(&T[c][moff]);
            *(short8v*)(YT + ((long)bb2 * 256 + fbase + c) * 1024 + nodeBase + moff) = vv;
        }
    }
}

// ---------------------------------------------------------------------------
// out = relu( Z + adj(u8 fixed)@Y + b0 + b1 [+res] ).  u8-A via
// global_load_lds, VALU dequant; fused epilogue. 8 waves, 128x128, BK=64,
// 3-stage 72KB, vmcnt(3). Batch->XCD pin. grid 256 x 512.
// ---------------------------------------------------------------------------
__global__ __launch_bounds__(512) void k_agg2(
    const u8* __restrict__ A8,
    const u16* __restrict__ YT,
    const u16* __restrict__ Z,
    const float* __restrict__ b0, const float* __restrict__ b1,
    const u16* __restrict__ res,
    u16* __restrict__ Out) {

    __shared__ u16 lds[36864];
    const int BUF = 12288;

    int t = threadIdx.x;
    int lane = t & 63, w = t >> 6;
    int wr = w >> 1, wc = w & 1;

    int h = blockIdx.x;
    int bz = h & 15, tt = h >> 4;
    int bx = tt & 1, by = tt >> 1;
    long row0 = (long)by * 128;
    int c0 = bx * 128;

    const u8*  Ap = A8 + (long)bz * NN * NN;
    const u16* Bp = YT + (long)bz * 256 * 1024;
    long obase = (long)bz * NN * 256;

    f32x4 acc[2][4] = {};

    int ar = t >> 2, ac = t & 3;
    int ac_src = ac ^ ((ar & 7) >> 1);

    auto stage = [&](int s, int bufbase) {
        int kt = s * 64;
        u8*  As = (u8*)(lds + bufbase);
        u16* Bs = lds + bufbase + 4096;
        __builtin_amdgcn_global_load_lds(
            (const __attribute__((address_space(1))) void*)(Ap + (row0 + ar) * NN + kt + ac_src * 16),
            (__attribute__((address_space(3))) void*)(As + ar * 64 + ac * 16), 16, 0, 0);
        #pragma unroll
        for (int q = 0; q < 2; ++q) {
            int rb = w * 16 + q * 8;
            int row = rb + (lane >> 3);
            int koff = kt + (((lane & 7) ^ (row & 7)) << 3);
            __builtin_amdgcn_global_load_lds(
                (const __attribute__((address_space(1))) void*)(Bp + (long)(c0 + row) * NN + koff),
                (__attribute__((address_space(3))) void*)(Bs + rb * 64), 16, 0, 0);
        }
    };

    stage(0, 0);
    stage(1, BUF);

    int curb = 0, stb = 2 * BUF;
    for (int s = 0; s < 16; ++s) {
        if (s < 15) { asm volatile("s_waitcnt vmcnt(3)" ::: "memory"); }
        else        { asm volatile("s_waitcnt vmcnt(0)" ::: "memory"); }
        __builtin_amdgcn_sched_barrier(0);
        __builtin_amdgcn_s_barrier();
        if (s + 2 < 16) stage(s + 2, stb);
        const u8*  As = (const u8*)(lds + curb);
        const u16* Bs = lds + curb + 4096;
        #pragma unroll
        for (int kk = 0; kk < 2; ++kk) {
            short8v a[2], bfr[4];
            #pragma unroll
            for (int m = 0; m < 2; ++m) {
                int row = wr * 32 + m * 16 + (lane & 15);
                int sfull = kk * 4 + (lane >> 4);
                int chunk = (sfull >> 1) ^ ((row & 7) >> 1);
                const unsigned* pq = (const unsigned*)(As + row * 64 + chunk * 16 + (sfull & 1) * 8);
                unsigned q0 = pq[0], q1 = pq[1];
                unsigned od[4];
                {
                    float f0 = (float)(q0 & 0xffu)         * 0x1p-18f;
                    float f1 = (float)((q0 >> 8) & 0xffu)  * 0x1p-18f;
                    float f2 = (float)((q0 >> 16) & 0xffu) * 0x1p-18f;
                    float f3 = (float)(q0 >> 24)           * 0x1p-18f;
                    od[0] = __builtin_amdgcn_perm(
                        __builtin_bit_cast(unsigned, f1), __builtin_bit_cast(unsigned, f0), 0x07060302u);
                    od[1] = __builtin_amdgcn_perm(
                        __builtin_bit_cast(unsigned, f3), __builtin_bit_cast(unsigned, f2), 0x07060302u);
                }
                {
                    float f0 = (float)(q1 & 0xffu)         * 0x1p-18f;
                    float f1 = (float)((q1 >> 8) & 0xffu)  * 0x1p-18f;
                    float f2 = (float)((q1 >> 16) & 0xffu) * 0x1p-18f;
                    float f3 = (float)(q1 >> 24)           * 0x1p-18f;
                    od[2] = __builtin_amdgcn_perm(
                        __builtin_bit_cast(unsigned, f1), __builtin_bit_cast(unsigned, f0), 0x07060302u);
                    od[3] = __builtin_amdgcn_perm(
                        __builtin_bit_cast(unsigned, f3), __builtin_bit_cast(unsigned, f2), 0x07060302u);
                }
                a[m] = __builtin_bit_cast(short8v, *(uint4*)od);
            }
            #pragma unroll
            for (int n = 0; n < 4; ++n) {
                int row = wc * 64 + n * 16 + (lane & 15);
                int sl = (kk * 4 + (lane >> 4)) ^ (row & 7);
                bfr[n] = *(const short8v*)(Bs + row * 64 + sl * 8);
            }
            #pragma unroll
            for (int m = 0; m < 2; ++m)
                #pragma unroll
                for (int n = 0; n < 4; ++n)
                    acc[m][n] = __builtin_amdgcn_mfma_f32_16x16x32_bf16(
                        a[m], bfr[n], acc[m][n], 0, 0, 0);
        }
        curb += BUF; if (curb == 3 * BUF) curb = 0;
        stb  += BUF; if (stb  == 3 * BUF) stb  = 0;
    }

    int mbase = wr * 32, nbase = wc * 64;
    #pragma unroll
    for (int m = 0; m < 2; ++m)
        #pragma unroll
        for (int n = 0; n < 4; ++n)
            #pragma unroll
            for (int r = 0; r < 4; ++r) {
                int rr = mbase + m * 16 + (lane >> 4) * 4 + r;
                int cc = nbase + n * 16 + (lane & 15);
                long grow = obase + (row0 + rr) * 256 + c0 + cc;
                int gcol = c0 + cc;
                float v = acc[m][n][r] + bf2f(Z[grow]) + b0[gcol] + b1[gcol];
                if (res) v += bf2f(res[grow]);
                v = fmaxf(v, 0.f);
                Out[grow] = f2bf(v);
            }
}

// ---------------------------------------------------------------------------
// FC head: 8 lanes per node, shfl reduce.
// ---------------------------------------------------------------------------
__global__ __launch_bounds__(256) void k_fc(const u16* __restrict__ Hf,
                     const float* __restrict__ fcW, const float* __restrict__ fcb,
                     const float* __restrict__ base_point,
                     const float* __restrict__ mask,
                     float* __restrict__ out, float* __restrict__ G) {
    int t = threadIdx.x;
    int w = t >> 6, l = t & 63;
    int bn = blockIdx.x * 32 + w * 8 + (l >> 3);
    int kc = (l & 7) * 32;
    const u16* hr = Hf + (long)bn * SS + kc;
    float a0 = 0.f, a1 = 0.f;
    #pragma unroll
    for (int j = 0; j < 32; j += 8) {
        short8v v = *(const short8v*)(hr + j);
        #pragma unroll
        for (int jj = 0; jj < 8; ++jj) {
            float f = bf2f((u16)v[jj]);
            a0 += f * fcW[kc + j + jj];
            a1 += f * fcW[SS + kc + j + jj];
        }
    }
    #pragma unroll
    for (int off = 1; off < 8; off <<= 1) {
        a0 += __shfl_xor(a0, off);
        a1 += __shfl_xor(a1, off);
    }
    if ((l & 7) == 0) {
        a0 += fcb[0]; a1 += fcb[1];
        float m  = mask[bn];
        float p0 = base_point[bn * 2 + 0], p1 = base_point[bn * 2 + 1];
        float g0 = a0 * m, g1 = a1 * m;
        out[16 + bn * 2 + 0] = p0 + g0;
        out[16 + bn * 2 + 1] = p1 + g1;
        out[16 + BN * 2 + bn * 2 + 0] = a0;
        out[16 + BN * 2 + bn * 2 + 1] = a1;
        G[bn * 2 + 0] = g0;
        G[bn * 2 + 1] = g1;
    }
}

// ---------------------------------------------------------------------------
// AG = adj @ G (u8 fixed adj); one wave per output row
// ---------------------------------------------------------------------------
__global__ __launch_bounds__(256) void k_adjg(const u8* __restrict__ A8,
                                              const float* __restrict__ G,
                                              float* __restrict__ AG) {
    int w = threadIdx.x >> 6, lane = threadIdx.x & 63;
    long row = (long)blockIdx.x * 4 + w;
    int b = (int)(row >> 10);
    const u8* ar = A8 + ((long)b * NN + (row & 1023)) * NN;
    const float* Gb = G + (long)b * NN * 2;
    float s0 = 0.f, s1 = 0.f;
    int k0 = lane * 16;
    uint4 v = *(const uint4*)(ar + k0);
    unsigned arr[4] = {v.x, v.y, v.z, v.w};
    #pragma unroll
    for (int i2 = 0; i2 < 4; ++i2) {
        #pragma unroll
        for (int bs = 0; bs < 4; ++bs) {
            float a = (float)((arr[i2] >> (8 * bs)) & 0xffu);
            int k = k0 + i2 * 4 + bs;
            s0 += a * Gb[k * 2 + 0];
            s1 += a * Gb[k * 2 + 1];
        }
    }
    #pragma unroll
    for (int off = 32; off; off >>= 1) {
        s0 += __shfl_down(s0, off);
        s1 += __shfl_down(s1, off);
    }
    if (lane == 0) {
        AG[row * 2 + 0] = s0 * 0x1p-18f;
        AG[row * 2 + 1] = s1 * 0x1p-18f;
    }
}

// ---------------------------------------------------------------------------
// energy
// ---------------------------------------------------------------------------
__global__ __launch_bounds__(256) void k_energy(const float* __restrict__ G,
                                                const float* __restrict__ AG,
                                                float* __restrict__ out) {
    __shared__ float red[256];
    int b = blockIdx.x, t = threadIdx.x;
    float s = 0.f;
    for (int n = t; n < NN; n += 256) {
        int bn = b * NN + n;
        float dx = G[bn * 2 + 0] - AG[bn * 2 + 0];
        float dy = G[bn * 2 + 1] - AG[bn * 2 + 1];
        s += sqrtf(dx * dx + dy * dy + 1e-10f);
    }
    red[t] = s;
    __syncthreads();
    for (int off = 128; off > 0; off >>= 1) {
        if (t < off) red[t] += red[t + off];
        __syncthreads();
    }
    if (t == 0) out[b] = red[0] / (float)NN;
}

// ---------------------------------------------------------------------------
extern "C" void kernel_launch(void* const* d_in, const int* in_sizes, int n_in,
                              void* d_out, int out_size, void* d_ws, size_t ws_size,
                              hipStream_t stream) {
    const float* features   = (const float*)d_in[0];
    const float* base_point = (const float*)d_in[1];
    const float* adj        = (const float*)d_in[2];
    const float* mask       = (const float*)d_in[3];
    const float* first_W    = (const float*)d_in[4];
    const float* first_b    = (const float*)d_in[5];
    const float* mid_W      = (const float*)d_in[6];
    const float* mid_b      = (const float*)d_in[7];
    const float* last_W     = (const float*)d_in[8];
    const float* last_b     = (const float*)d_in[9];
    const float* fc_W       = (const float*)d_in[10];
    const float* fc_b       = (const float*)d_in[11];
    float* out = (float*)d_out;
    char* p = (char*)d_ws;

    // Region 0 (67.1 MB): featT first; then reused for Z / Hn / On / G / AG.
    u16*  featT = (u16*)p;
    u16*  Z     = (u16*)(p + 16777216);                      //  8.39 MB
    u16*  Hn    = (u16*)(p + 16777216 + 8388608);            //  8.39 MB
    u16*  On    = (u16*)(p + 16777216 + 2 * 8388608);        //  8.39 MB
    float* G    = (float*)(p + 16777216 + 3 * 8388608);      //  0.13 MB
    float* AG   = G + (size_t)BN * 2;                        //  0.13 MB
    p += (size_t)BB * 16384 * 128 * 2;                       // 67108864

    u16* Xh  = (u16*)p;  p += (size_t)BN * K1 * 2;
    u16* YT  = (u16*)p;  p += (size_t)BB * 256 * 1024 * 2;
    u16* Whf = (u16*)p;  p += (size_t)2 * 256 * K1 * 2;
    u16* Whm = (u16*)p;  p += (size_t)6 * 4 * 256 * 256 * 2;
    u16* Whl = (u16*)p;  p += (size_t)2 * 256 * 256 * 2;
    u8* adjq = (u8*)p;   p += (size_t)BB * NN * NN;          // 16.78 MB (non-aliased)

    k_prep<<<4800, 256, 0, stream>>>(adj, adjq, features, featT,
                                     mid_W, Whm, last_W, Whl, first_W, Whf);
    k_interp<<<BN / 4, 256, 0, stream>>>(featT, base_point, Xh);

    dim3 gWg(4, 128), blk(512);

    // first layer: [Z|Y] = Xh @ [W0|W1]^T ; Hn = relu(Z + adj@Y + b)
    k_wg<<<gWg, blk, 0, stream>>>(Xh, K1, 3, Whf, K1, Z, YT);
    k_agg2<<<256, blk, 0, stream>>>(adjq, YT, Z, first_b, first_b + 256, nullptr, Hn);

    for (int i = 0; i < 6; ++i) {
        const u16* W = Whm + (size_t)i * 4 * 256 * 256;
        const float* bb = mid_b + (size_t)i * 4 * 256;
        k_wg<<<gWg, blk, 0, stream>>>(Hn, 256, 4, W, 256, Z, YT);
        k_agg2<<<256, blk, 0, stream>>>(adjq, YT, Z, bb, bb + 256, nullptr, On);
        k_wg<<<gWg, blk, 0, stream>>>(On, 256, 4, W + 2 * 65536, 256, Z, YT);
        k_agg2<<<256, blk, 0, stream>>>(adjq, YT, Z, bb + 512, bb + 768, Hn, Hn);
    }

    // last layer
    k_wg<<<gWg, blk, 0, stream>>>(Hn, 256, 4, Whl, 256, Z, YT);
    k_agg2<<<256, blk, 0, stream>>>(adjq, YT, Z, last_b, last_b + 256, nullptr, On);

    // head + energy
    k_fc<<<BN / 32, 256, 0, stream>>>(On, fc_W, fc_b, base_point, mask, out, G);
    k_adjg<<<BN / 4, 256, 0, stream>>>(adjq, G, AG);
    k_energy<<<BB, 256, 0, stream>>>(G, AG, out);
}